// Round 5
// baseline (806.993 us; speedup 1.0000x reference)
//
#include <hip/hip_runtime.h>
#include <stdint.h>

// ---------------------------------------------------------------------------
// InvariantPointAttention, N=20000 nodes, E=640000 edges, H=4, S=64, QK=VD=8
//
// Pipeline (all on `stream`):
//   k_zero / k_count / k_scan / k_fill : CSR build (edges sorted by dest i);
//              sj[pos]=source node, se[pos]=original edge id
//   k_proj   : tiled per-node projections (32 nodes/block, transposed LDS
//              s-tile): q_s,k_s (bf16 Nx256), q_v,k_v (rot+trans bf16 Nx96),
//              v_s (f32 Nx256), v_loc (raw points f32 Nx96, PLANE layout).
//              out_scalar == v_s and out_vec == raw v_loc exactly
//              (softmax weights sum to 1; R^-1(R(v)+t-t)=v).
//   k_seg    : FUSED per-segment kernel (wave per node): z-projection
//              (weights via uniform s_load), logits, online softmax, and
//              pair aggregation -> out_pair.  Per-edge intermediates live
//              only in registers/LDS.  No atomics, no barriers (wave-local
//              LDS slices + __threadfence_block ordering).
//   k_out    : assemble feats[448] per node + feats @ Wout + bout -> out
// ---------------------------------------------------------------------------

#define C_SQRT83  1.6329931618554518f   // sqrt(8/3)
#define C_SQRT13  0.5773502691896258f   // sqrt(1/3)
#define C_VEC    -0.04811252243246881f  // -0.5*sqrt(1/108)

__device__ __forceinline__ unsigned short f2bf(float f){
  unsigned u = __float_as_uint(f);
  u += 0x7fffu + ((u >> 16) & 1u);          // round-to-nearest-even
  return (unsigned short)(u >> 16);
}
__device__ __forceinline__ unsigned pack2(float a, float b){
  return (unsigned)f2bf(a) | ((unsigned)f2bf(b) << 16);
}
__device__ __forceinline__ float bflo(unsigned u){ return __uint_as_float(u << 16); }
__device__ __forceinline__ float bfhi(unsigned u){ return __uint_as_float(u & 0xffff0000u); }

__device__ __forceinline__ void quat_rot(float w, float ux, float uy, float uz,
                                         float vx, float vy, float vz,
                                         float& ox, float& oy, float& oz){
  float cx = uy*vz - uz*vy;
  float cy = uz*vx - ux*vz;
  float cz = ux*vy - uy*vx;
  float dx = uy*cz - uz*cy;
  float dy = uz*cx - ux*cz;
  float dz = ux*cy - uy*cx;
  ox = vx + 2.f*(w*cx + dx);
  oy = vy + 2.f*(w*cy + dy);
  oz = vz + 2.f*(w*cz + dz);
}

// -------------------------------- CSR build --------------------------------

__global__ __launch_bounds__(256) void k_zero(unsigned* __restrict__ counts, int n){
  int g = blockIdx.x*256 + threadIdx.x;
  if (g < n) counts[g] = 0u;
}

__global__ __launch_bounds__(256) void k_count(const int* __restrict__ ei,
                                               unsigned* __restrict__ counts, int ne){
  int e = blockIdx.x*256 + threadIdx.x;
  if (e >= ne) return;
  atomicAdd(&counts[ei[e]], 1u);
}

__global__ __launch_bounds__(256) void k_scan(const unsigned* __restrict__ counts,
                                              unsigned* __restrict__ row_off,
                                              unsigned* __restrict__ cursor, int n){
  __shared__ unsigned part[256];
  int t = threadIdx.x;
  int chunk = (n + 255) >> 8;
  int s0 = t*chunk, s1 = min(s0 + chunk, n);
  unsigned sum = 0;
  for (int k = s0; k < s1; ++k) sum += counts[k];
  part[t] = sum; __syncthreads();
  for (int off = 1; off < 256; off <<= 1){
    unsigned v = (t >= off) ? part[t-off] : 0u;
    __syncthreads();
    part[t] += v;
    __syncthreads();
  }
  unsigned run = (t == 0) ? 0u : part[t-1];
  for (int k = s0; k < s1; ++k){
    row_off[k] = run; cursor[k] = run; run += counts[k];
  }
  if (t == 255) row_off[n] = part[255];
}

__global__ __launch_bounds__(256) void k_fill(const int* __restrict__ ei,
                                              unsigned* __restrict__ cursor,
                                              unsigned* __restrict__ sj,
                                              unsigned* __restrict__ se, int ne){
  int e = blockIdx.x*256 + threadIdx.x;
  if (e >= ne) return;
  int i = ei[e];
  unsigned pos = atomicAdd(&cursor[i], 1u);
  sj[pos] = (unsigned)ei[ne + e];
  se[pos] = (unsigned)e;
}

// ------------------------------ node projections ----------------------------
// Block = 32 nodes, 256 threads.  s tile TRANSPOSED in LDS: stT[k][node].

#define BN 32

__device__ __forceinline__ void pass256(const float* __restrict__ W,
                                        const float stT[64][40], int cg, int sl,
                                        float acc[8][4]){
  #pragma unroll
  for (int i=0;i<8;i++){ acc[i][0]=0.f; acc[i][1]=0.f; acc[i][2]=0.f; acc[i][3]=0.f; }
  #pragma unroll 4
  for (int k = 0; k < 64; ++k){
    const float4 w  = *(const float4*)(W + (size_t)k*256 + cg*4);
    const float4 n0 = *(const float4*)&stT[k][sl*8];
    const float4 n1 = *(const float4*)&stT[k][sl*8+4];
    acc[0][0]+=n0.x*w.x; acc[0][1]+=n0.x*w.y; acc[0][2]+=n0.x*w.z; acc[0][3]+=n0.x*w.w;
    acc[1][0]+=n0.y*w.x; acc[1][1]+=n0.y*w.y; acc[1][2]+=n0.y*w.z; acc[1][3]+=n0.y*w.w;
    acc[2][0]+=n0.z*w.x; acc[2][1]+=n0.z*w.y; acc[2][2]+=n0.z*w.z; acc[2][3]+=n0.z*w.w;
    acc[3][0]+=n0.w*w.x; acc[3][1]+=n0.w*w.y; acc[3][2]+=n0.w*w.z; acc[3][3]+=n0.w*w.w;
    acc[4][0]+=n1.x*w.x; acc[4][1]+=n1.x*w.y; acc[4][2]+=n1.x*w.z; acc[4][3]+=n1.x*w.w;
    acc[5][0]+=n1.y*w.x; acc[5][1]+=n1.y*w.y; acc[5][2]+=n1.y*w.z; acc[5][3]+=n1.y*w.w;
    acc[6][0]+=n1.z*w.x; acc[6][1]+=n1.z*w.y; acc[6][2]+=n1.z*w.z; acc[6][3]+=n1.z*w.w;
    acc[7][0]+=n1.w*w.x; acc[7][1]+=n1.w*w.y; acc[7][2]+=n1.w*w.z; acc[7][3]+=n1.w*w.w;
  }
}

__device__ __forceinline__ void pass96(const float* __restrict__ W,
                                       const float stT[64][40], int cgp, int slp,
                                       float acc[4][4]){
  #pragma unroll
  for (int i=0;i<4;i++){ acc[i][0]=0.f; acc[i][1]=0.f; acc[i][2]=0.f; acc[i][3]=0.f; }
  if (cgp >= 24) return;
  #pragma unroll 4
  for (int k = 0; k < 64; ++k){
    const float4 w = *(const float4*)(W + (size_t)k*96 + cgp*4);
    const float4 nv = *(const float4*)&stT[k][slp*4];
    acc[0][0]+=nv.x*w.x; acc[0][1]+=nv.x*w.y; acc[0][2]+=nv.x*w.z; acc[0][3]+=nv.x*w.w;
    acc[1][0]+=nv.y*w.x; acc[1][1]+=nv.y*w.y; acc[1][2]+=nv.y*w.z; acc[1][3]+=nv.y*w.w;
    acc[2][0]+=nv.z*w.x; acc[2][1]+=nv.z*w.y; acc[2][2]+=nv.z*w.z; acc[2][3]+=nv.z*w.w;
    acc[3][0]+=nv.w*w.x; acc[3][1]+=nv.w*w.y; acc[3][2]+=nv.w*w.z; acc[3][3]+=nv.w*w.w;
  }
}

__global__ __launch_bounds__(256) void k_proj(
    const float* __restrict__ s, const float* __restrict__ quat, const float* __restrict__ trans,
    const float* __restrict__ Wqs, const float* __restrict__ Wks, const float* __restrict__ Wvs,
    const float* __restrict__ Wqv, const float* __restrict__ Wkv, const float* __restrict__ Wvv,
    unsigned* __restrict__ qs, unsigned* __restrict__ ks, float* __restrict__ vs,
    unsigned* __restrict__ qv, unsigned* __restrict__ kv, float* __restrict__ vv, int n)
{
  __shared__ float stT[64][40];    // transposed s tile (k-major), 16B-aligned cols
  __shared__ float pt[BN][97];     // point staging (x:0..31, y:32..63, z:64..95)
  const int tid = threadIdx.x;
  const int node0 = blockIdx.x * BN;

  #pragma unroll
  for (int r = 0; r < 2; ++r){
    const int idx = tid + r*256;          // float4 index
    const int nd = idx >> 4, c4 = idx & 15;
    const int g = node0 + nd;
    float4 v = make_float4(0.f,0.f,0.f,0.f);
    if (g < n) v = *(const float4*)(s + (size_t)g*64 + c4*4);
    stT[c4*4+0][nd]=v.x; stT[c4*4+1][nd]=v.y; stT[c4*4+2][nd]=v.z; stT[c4*4+3][nd]=v.w;
  }
  __syncthreads();

  const int cg = tid & 63, sl = tid >> 6;
  const int cgp = tid & 31, slp = tid >> 5;
  float acc[8][4];

  pass256(Wqs, stT, cg, sl, acc);
  #pragma unroll
  for (int i=0;i<8;i++){
    const int g = node0 + sl*8 + i;
    if (g < n){
      uint2 u; u.x = pack2(acc[i][0],acc[i][1]); u.y = pack2(acc[i][2],acc[i][3]);
      *(uint2*)(qs + (size_t)g*128 + cg*2) = u;
    }
  }
  pass256(Wks, stT, cg, sl, acc);
  #pragma unroll
  for (int i=0;i<8;i++){
    const int g = node0 + sl*8 + i;
    if (g < n){
      uint2 u; u.x = pack2(acc[i][0],acc[i][1]); u.y = pack2(acc[i][2],acc[i][3]);
      *(uint2*)(ks + (size_t)g*128 + cg*2) = u;
    }
  }
  pass256(Wvs, stT, cg, sl, acc);
  #pragma unroll
  for (int i=0;i<8;i++){
    const int g = node0 + sl*8 + i;
    if (g < n){
      float4 f; f.x=acc[i][0]; f.y=acc[i][1]; f.z=acc[i][2]; f.w=acc[i][3];
      *(float4*)(vs + (size_t)g*256 + cg*4) = f;
    }
  }

  float pac[4][4];

  // q_v: rotate + translate -> bf16
  pass96(Wqv, stT, cgp, slp, pac);
  __syncthreads();
  if (cgp < 24){
    #pragma unroll
    for (int i=0;i<4;i++){
      #pragma unroll
      for (int c=0;c<4;c++) pt[slp*4+i][cgp*4+c] = pac[i][c];
    }
  }
  __syncthreads();
  #pragma unroll
  for (int r = 0; r < 2; ++r){
    const int t2 = tid + r*256;
    const int nd = t2 >> 4, pp = t2 & 15;
    const int g = node0 + nd;
    if (g < n){
      const float4 q4 = *(const float4*)(quat + (size_t)g*4);
      const float tx = trans[(size_t)g*3], ty = trans[(size_t)g*3+1], tz = trans[(size_t)g*3+2];
      float x0,y0,z0,x1,y1,z1;
      quat_rot(q4.x,q4.y,q4.z,q4.w, pt[nd][2*pp],   pt[nd][32+2*pp],   pt[nd][64+2*pp],   x0,y0,z0);
      quat_rot(q4.x,q4.y,q4.z,q4.w, pt[nd][2*pp+1], pt[nd][32+2*pp+1], pt[nd][64+2*pp+1], x1,y1,z1);
      x0+=tx; y0+=ty; z0+=tz; x1+=tx; y1+=ty; z1+=tz;
      unsigned* d = qv + (size_t)g*48 + pp*3;
      d[0] = pack2(x0,y0); d[1] = pack2(z0,x1); d[2] = pack2(y1,z1);
    }
  }

  // k_v: rotate + translate -> bf16
  pass96(Wkv, stT, cgp, slp, pac);
  __syncthreads();
  if (cgp < 24){
    #pragma unroll
    for (int i=0;i<4;i++){
      #pragma unroll
      for (int c=0;c<4;c++) pt[slp*4+i][cgp*4+c] = pac[i][c];
    }
  }
  __syncthreads();
  #pragma unroll
  for (int r = 0; r < 2; ++r){
    const int t2 = tid + r*256;
    const int nd = t2 >> 4, pp = t2 & 15;
    const int g = node0 + nd;
    if (g < n){
      const float4 q4 = *(const float4*)(quat + (size_t)g*4);
      const float tx = trans[(size_t)g*3], ty = trans[(size_t)g*3+1], tz = trans[(size_t)g*3+2];
      float x0,y0,z0,x1,y1,z1;
      quat_rot(q4.x,q4.y,q4.z,q4.w, pt[nd][2*pp],   pt[nd][32+2*pp],   pt[nd][64+2*pp],   x0,y0,z0);
      quat_rot(q4.x,q4.y,q4.z,q4.w, pt[nd][2*pp+1], pt[nd][32+2*pp+1], pt[nd][64+2*pp+1], x1,y1,z1);
      x0+=tx; y0+=ty; z0+=tz; x1+=tx; y1+=ty; z1+=tz;
      unsigned* d = kv + (size_t)g*48 + pp*3;
      d[0] = pack2(x0,y0); d[1] = pack2(z0,x1); d[2] = pack2(y1,z1);
    }
  }

  // v_v: raw (pre-rotation) points == out_vec; f32 PLANE layout
  pass96(Wvv, stT, cgp, slp, pac);
  __syncthreads();
  if (cgp < 24){
    #pragma unroll
    for (int i=0;i<4;i++){
      #pragma unroll
      for (int c=0;c<4;c++) pt[slp*4+i][cgp*4+c] = pac[i][c];
    }
  }
  __syncthreads();
  #pragma unroll
  for (int r = 0; r < 12; ++r){
    const int idx = tid + r*256;
    const int nd = idx / 96, col = idx - nd*96;
    const int g = node0 + nd;
    if (g < n) vv[(size_t)g*96 + col] = pt[nd][col];
  }
}

// ---------------------- fused per-segment edge kernel -----------------------
// Wave per node.  Per 64-edge chunk:
//   pass A (lane=edge): z-proj (uniform weights) -> bias,pz; gather qs[j],
//     kv[j]; dot/dist vs LDS-staged ks[i],qv[i]; logits -> LDS, pz -> LDS;
//     chunk max via shfl butterfly; online-softmax merge (rescale acc,S).
//   pass B (lane=(h,c)): w=exp(l-m); S+=w; acc += w*pz[c].
// Only out_pair (Nx64) is written.

__global__ __launch_bounds__(256) void k_seg(
    const float* __restrict__ z,
    const unsigned* __restrict__ sj, const unsigned* __restrict__ se,
    const unsigned* __restrict__ row_off,
    const float* __restrict__ Wb,  const float* __restrict__ bb,
    const float* __restrict__ Wdz, const float* __restrict__ bdz,
    const float* __restrict__ hwts,
    const unsigned* __restrict__ qs, const unsigned* __restrict__ ksc,
    const unsigned* __restrict__ qv, const unsigned* __restrict__ kv,
    float* __restrict__ out_pair, int n)
{
  __shared__ uint4    sh_ks[4][32];      // ks[i] row (512B)
  __shared__ uint4    sh_qv[4][12];      // qv[i] row (192B)
  __shared__ float    sh_l [4][64][4];   // chunk logits
  __shared__ unsigned sh_pz[4][64][8];   // chunk pz (bf16x2)

  const int wv   = threadIdx.x >> 6;
  const int lane = threadIdx.x & 63;
  const int node = blockIdx.x*4 + wv;
  if (node >= n) return;

  const int beg = (int)row_off[node], end = (int)row_off[node+1];

  if (lane < 32)      sh_ks[wv][lane]    = ((const uint4*)(ksc + (size_t)node*128))[lane];
  else if (lane < 44) sh_qv[wv][lane-32] = ((const uint4*)(qv  + (size_t)node*48))[lane-32];
  __threadfence_block();

  float hwv[4];
  #pragma unroll
  for (int h=0;h<4;h++) hwv[h] = C_VEC * log1pf(__expf(hwts[h]));

  const int hl = lane >> 4, cl = lane & 15;
  float m4[4] = {-3.0e38f,-3.0e38f,-3.0e38f,-3.0e38f};
  float accO = 0.f, S = 0.f;

  for (int base = beg; base < end; base += 64){
    const int p = base + lane;
    const bool act = (p < end);
    const unsigned j = act ? sj[p] : 0u;
    const unsigned e = act ? se[p] : 0u;

    // ---- z-projection: bias[4] + pz[16] (wave-uniform weight reads) ----
    float b4[4]; float pz[16];
    b4[0]=bb[0]; b4[1]=bb[1]; b4[2]=bb[2]; b4[3]=bb[3];
    #pragma unroll
    for (int c=0;c<16;c++) pz[c] = bdz[c];
    const float4* zr = (const float4*)(z + (size_t)e*64);
    #pragma unroll 4
    for (int k4 = 0; k4 < 16; ++k4){
      const float4 zv = zr[k4];
      const float zk[4] = {zv.x, zv.y, zv.z, zv.w};
      #pragma unroll
      for (int kk = 0; kk < 4; ++kk){
        const int k = k4*4 + kk;
        const float zs = zk[kk];
        #pragma unroll
        for (int c=0;c<4;c++)  b4[c] += zs * Wb[k*4+c];
        #pragma unroll
        for (int c=0;c<16;c++) pz[c] += zs * Wdz[k*16+c];
      }
    }

    // ---- scalar dot per head: ks[i](LDS) . qs[j](global) ----
    const uint4* qj = (const uint4*)(qs + (size_t)j*128);
    float sdot[4];
    #pragma unroll
    for (int h = 0; h < 4; ++h){
      uint4 qb[8];
      #pragma unroll
      for (int c=0;c<8;c++) qb[c] = qj[h*8+c];
      float acc = 0.f;
      #pragma unroll
      for (int c=0;c<8;c++){
        const uint4 a = sh_ks[wv][h*8+c];
        const uint4 b = qb[c];
        acc += bflo(a.x)*bflo(b.x) + bfhi(a.x)*bfhi(b.x);
        acc += bflo(a.y)*bflo(b.y) + bfhi(a.y)*bfhi(b.y);
        acc += bflo(a.z)*bflo(b.z) + bfhi(a.z)*bfhi(b.z);
        acc += bflo(a.w)*bflo(b.w) + bfhi(a.w)*bfhi(b.w);
      }
      sdot[h] = acc;
    }

    // ---- vector dist per head: |qv[i](LDS) - kv[j](global)|^2 ----
    const uint4* kj = (const uint4*)(kv + (size_t)j*48);
    float vsum[4];
    #pragma unroll
    for (int h = 0; h < 4; ++h){
      uint4 kb[3];
      #pragma unroll
      for (int c=0;c<3;c++) kb[c] = kj[h*3+c];
      float acc = 0.f, d;
      #pragma unroll
      for (int c=0;c<3;c++){
        const uint4 a = sh_qv[wv][h*3+c];
        const uint4 b = kb[c];
        d=bflo(a.x)-bflo(b.x); acc+=d*d; d=bfhi(a.x)-bfhi(b.x); acc+=d*d;
        d=bflo(a.y)-bflo(b.y); acc+=d*d; d=bfhi(a.y)-bfhi(b.y); acc+=d*d;
        d=bflo(a.z)-bflo(b.z); acc+=d*d; d=bfhi(a.z)-bfhi(b.z); acc+=d*d;
        d=bflo(a.w)-bflo(b.w); acc+=d*d; d=bfhi(a.w)-bfhi(b.w); acc+=d*d;
      }
      vsum[h] = acc;
    }

    // ---- logits; stage chunk into LDS ----
    float l4[4];
    #pragma unroll
    for (int h = 0; h < 4; ++h)
      l4[h] = act ? (C_SQRT83*sdot[h] + C_SQRT13*b4[h] + hwv[h]*vsum[h]) : -3.0e38f;

    *(float4*)&sh_l[wv][lane][0] = make_float4(l4[0], l4[1], l4[2], l4[3]);
    {
      uint4 u0, u1;
      u0.x=pack2(pz[0],pz[1]);   u0.y=pack2(pz[2],pz[3]);
      u0.z=pack2(pz[4],pz[5]);   u0.w=pack2(pz[6],pz[7]);
      u1.x=pack2(pz[8],pz[9]);   u1.y=pack2(pz[10],pz[11]);
      u1.z=pack2(pz[12],pz[13]); u1.w=pack2(pz[14],pz[15]);
      uint4* d = (uint4*)&sh_pz[wv][lane][0];
      d[0]=u0; d[1]=u1;
    }

    // ---- chunk max (64-lane butterfly), online merge ----
    float cm[4] = {l4[0], l4[1], l4[2], l4[3]};
    #pragma unroll
    for (int msk = 1; msk < 64; msk <<= 1){
      #pragma unroll
      for (int h=0;h<4;h++) cm[h] = fmaxf(cm[h], __shfl_xor(cm[h], msk));
    }
    float mn[4];
    #pragma unroll
    for (int h=0;h<4;h++) mn[h] = fmaxf(m4[h], cm[h]);
    const float scale = __expf(m4[hl] - mn[hl]);   // 0 on first chunk
    accO *= scale; S *= scale;
    #pragma unroll
    for (int h=0;h<4;h++) m4[h] = mn[h];

    __threadfence_block();

    // ---- pass B: aggregate (lane = (h, c)) ----
    const int cnt = min(64, end - base);
    const float mh = m4[hl];
    for (int p2 = 0; p2 < cnt; ++p2){
      const float w = __expf(sh_l[wv][p2][hl] - mh);
      S += w;
      const unsigned u = sh_pz[wv][p2][cl>>1];
      const float pzv = (cl & 1) ? bfhi(u) : bflo(u);
      accO += w * pzv;
    }
    __threadfence_block();
  }

  const float inv = (S > 0.f) ? (1.f/S) : 0.f;
  out_pair[(size_t)node*64 + lane] = accO * inv;
}

// --------------------- feats assembly + output GEMM ------------------------

__global__ __launch_bounds__(256) void k_out(
    const float* __restrict__ vs, const float* __restrict__ vv,
    const float* __restrict__ out_pair, const unsigned* __restrict__ row_off,
    const float* __restrict__ quat, const float* __restrict__ trans,
    const float* __restrict__ Wout, const float* __restrict__ bout,
    float* __restrict__ out, int n)
{
  __shared__ float feats[32][448];
  __shared__ int degs[32];
  const int tid = threadIdx.x;
  const int node0 = blockIdx.x*32;

  if (tid < 32){
    const int g = node0 + tid;
    degs[tid] = (g < n) ? (int)(row_off[g+1] - row_off[g]) : 1;
  }
  __syncthreads();

  for (int x = tid; x < 32*256; x += 256){
    const int nd = x >> 8, c = x & 255;
    const int g = node0 + nd;
    feats[nd][c] = (g < n && degs[nd] > 0) ? vs[(size_t)g*256 + c] : 0.f;
  }
  for (int x = tid; x < 32*64; x += 256){
    const int nd = x >> 6, c = x & 63;
    const int g = node0 + nd;
    feats[nd][384 + c] = (g < n) ? out_pair[(size_t)g*64 + c] : 0.f;
  }
  for (int x = tid; x < 32*32; x += 256){
    const int nd = x >> 5, pt = x & 31;
    const int g = node0 + nd;
    float X=0.f, Y=0.f, Z=0.f;
    if (g < n){
      if (degs[nd] > 0){
        X = vv[(size_t)g*96 + pt];
        Y = vv[(size_t)g*96 + 32 + pt];
        Z = vv[(size_t)g*96 + 64 + pt];
      } else {
        const float4 q4 = *(const float4*)(quat + (size_t)g*4);
        const float tx = trans[(size_t)g*3], ty = trans[(size_t)g*3+1], tz = trans[(size_t)g*3+2];
        quat_rot(q4.x, -q4.y, -q4.z, -q4.w, -tx, -ty, -tz, X, Y, Z);
      }
    }
    feats[nd][256 + pt] = X;
    feats[nd][288 + pt] = Y;
    feats[nd][320 + pt] = Z;
    feats[nd][352 + pt] = sqrtf(X*X + Y*Y + Z*Z + 1e-8f);
  }
  __syncthreads();

  const int lane = tid & 63;
  const int wave = tid >> 6;
  float acc[8];
  #pragma unroll
  for (int q8=0;q8<8;q8++) acc[q8]=0.f;

  for (int k0 = 0; k0 < 448; k0 += 4){
    const float w0 = Wout[(size_t)(k0+0)*64 + lane];
    const float w1 = Wout[(size_t)(k0+1)*64 + lane];
    const float w2 = Wout[(size_t)(k0+2)*64 + lane];
    const float w3 = Wout[(size_t)(k0+3)*64 + lane];
    #pragma unroll
    for (int q8 = 0; q8 < 8; ++q8){
      const float4 f = *(const float4*)&feats[wave*8 + q8][k0];
      acc[q8] += f.x*w0 + f.y*w1 + f.z*w2 + f.w*w3;
    }
  }
  const float bo = bout[lane];
  #pragma unroll
  for (int q8 = 0; q8 < 8; ++q8){
    const int g = node0 + wave*8 + q8;
    if (g < n) out[(size_t)g*64 + lane] = acc[q8] + bo;
  }
}

// --------------------------------- launch ----------------------------------

extern "C" void kernel_launch(void* const* d_in, const int* in_sizes, int n_in,
                              void* d_out, int out_size, void* d_ws, size_t ws_size,
                              hipStream_t stream) {
  const float* s     = (const float*)d_in[0];
  const float* z     = (const float*)d_in[1];
  const int*   ei    = (const int*)  d_in[2];
  const float* quat  = (const float*)d_in[3];
  const float* trans = (const float*)d_in[4];
  const float* Wqs   = (const float*)d_in[5];
  const float* Wks   = (const float*)d_in[6];
  const float* Wvs   = (const float*)d_in[7];
  const float* Wqv   = (const float*)d_in[8];
  const float* Wkv   = (const float*)d_in[9];
  const float* Wvv   = (const float*)d_in[10];
  const float* Wb    = (const float*)d_in[11];
  const float* bb    = (const float*)d_in[12];
  const float* Wdz   = (const float*)d_in[13];
  const float* bdz   = (const float*)d_in[14];
  const float* hwts  = (const float*)d_in[15];
  const float* Wout  = (const float*)d_in[16];
  const float* bout  = (const float*)d_in[17];
  float* out = (float*)d_out;

  const int n  = in_sizes[0] / 64;   // 20000
  const int ne = in_sizes[1] / 64;   // 640000

  size_t off = 0;
  char* base = (char*)d_ws;
  auto take = [&](size_t bytes)->char* {
    char* p = base + off;
    off += (bytes + 255) & ~(size_t)255;
    return p;
  };
  unsigned* qs     = (unsigned*)take((size_t)n*512);    // bf16 N x 256
  unsigned* ks     = (unsigned*)take((size_t)n*512);    // bf16 N x 256
  unsigned* qvt    = (unsigned*)take((size_t)n*192);    // bf16 N x 96 (rot + t)
  unsigned* kvt    = (unsigned*)take((size_t)n*192);    // bf16 N x 96 (rot + t)
  float*    vs     = (float*)   take((size_t)n*1024);   // f32  N x 256
  float*    vv     = (float*)   take((size_t)n*384);    // f32  N x 96 (raw, planes)
  unsigned* counts = (unsigned*)take((size_t)n*4);
  unsigned* roff   = (unsigned*)take((size_t)(n+1)*4);
  unsigned* cur    = (unsigned*)take((size_t)n*4);
  unsigned* sj     = (unsigned*)take((size_t)ne*4);
  unsigned* se     = (unsigned*)take((size_t)ne*4);
  float*    opair  = (float*)   take((size_t)n*256);    // f32  N x 64
  (void)ws_size; (void)n_in; (void)out_size;

  const int gbE = (ne + 255) / 256;
  const int gbN = (n  + 255) / 256;

  k_zero <<<gbN, 256, 0, stream>>>(counts, n);
  k_count<<<gbE, 256, 0, stream>>>(ei, counts, ne);
  k_scan <<<1,   256, 0, stream>>>(counts, roff, cur, n);
  k_fill <<<gbE, 256, 0, stream>>>(ei, cur, sj, se, ne);
  k_proj <<<(n + BN - 1)/BN, 256, 0, stream>>>(s, quat, trans, Wqs, Wks, Wvs, Wqv, Wkv, Wvv,
                                               qs, ks, vs, qvt, kvt, vv, n);
  k_seg  <<<(n + 3)/4, 256, 0, stream>>>(z, sj, se, roff, Wb, bb, Wdz, bdz, hwts,
                                         qs, ks, qvt, kvt, opair, n);
  k_out  <<<(n + 31)/32, 256, 0, stream>>>(vs, vv, opair, roff, quat, trans,
                                           Wout, bout, out, n);
}

// Round 6
// 659.819 us; speedup vs baseline: 1.2231x; 1.2231x over previous
//
#include <hip/hip_runtime.h>
#include <stdint.h>

// ---------------------------------------------------------------------------
// InvariantPointAttention, N=20000 nodes, E=640000 edges, H=4, S=64, QK=VD=8
//
// Pipeline (all on `stream`):
//   memset(counts) / k_count / k_scan / k_fill : CSR build.  k_count stores
//       rank[e] (atomic return); k_fill is ATOMIC-FREE (pos=roff[i]+rank[e]).
//   k_proj   : tiled per-node projections (32 nodes/block, transposed LDS
//              s-tile): q_s,k_s (bf16 Nx256), q_v,k_v (rot+trans bf16 Nx96),
//              v_s (f32 Nx256), v_loc (raw points f32 Nx96, PLANE layout).
//              out_scalar == v_s and out_vec == raw v_loc exactly
//              (softmax weights sum to 1; R^-1(R(v)+t-t)=v).
//   k_edge   : per CSR edge (1 thread/edge): z-proj -> bias,pz; gather
//              q_s[j],k_v[j] vs k_s[i],q_v[i]; logits E x4 f32 + pz E x16
//              bf16, coalesced in CSR order.  (R2-proven structure.)
//   k_soft   : wave-per-node, register/shuffle only: per-head max+sum
//              (lane-parallel), then weighted pair aggregation with
//              lane=(e4,col) -> out_pair (Nx64), coalesced store.
//   k_out    : assemble feats[448] per node + feats @ Wout + bout -> out
// ---------------------------------------------------------------------------

#define C_SQRT83  1.6329931618554518f   // sqrt(8/3)
#define C_SQRT13  0.5773502691896258f   // sqrt(1/3)
#define C_VEC    -0.04811252243246881f  // -0.5*sqrt(1/108)

__device__ __forceinline__ unsigned short f2bf(float f){
  unsigned u = __float_as_uint(f);
  u += 0x7fffu + ((u >> 16) & 1u);          // round-to-nearest-even
  return (unsigned short)(u >> 16);
}
__device__ __forceinline__ unsigned pack2(float a, float b){
  return (unsigned)f2bf(a) | ((unsigned)f2bf(b) << 16);
}
__device__ __forceinline__ float bflo(unsigned u){ return __uint_as_float(u << 16); }
__device__ __forceinline__ float bfhi(unsigned u){ return __uint_as_float(u & 0xffff0000u); }

__device__ __forceinline__ void quat_rot(float w, float ux, float uy, float uz,
                                         float vx, float vy, float vz,
                                         float& ox, float& oy, float& oz){
  float cx = uy*vz - uz*vy;
  float cy = uz*vx - ux*vz;
  float cz = ux*vy - uy*vx;
  float dx = uy*cz - uz*cy;
  float dy = uz*cx - ux*cz;
  float dz = ux*cy - uy*cx;
  ox = vx + 2.f*(w*cx + dx);
  oy = vy + 2.f*(w*cy + dy);
  oz = vz + 2.f*(w*cz + dz);
}

// -------------------------------- CSR build --------------------------------

__global__ __launch_bounds__(256) void k_count(const int* __restrict__ ei,
                                               unsigned* __restrict__ counts,
                                               unsigned* __restrict__ rank, int ne){
  int e = blockIdx.x*256 + threadIdx.x;
  if (e >= ne) return;
  rank[e] = atomicAdd(&counts[ei[e]], 1u);
}

__global__ __launch_bounds__(256) void k_scan(const unsigned* __restrict__ counts,
                                              unsigned* __restrict__ row_off, int n){
  __shared__ unsigned part[256];
  int t = threadIdx.x;
  int chunk = (n + 255) >> 8;
  int s0 = t*chunk, s1 = min(s0 + chunk, n);
  unsigned sum = 0;
  for (int k = s0; k < s1; ++k) sum += counts[k];
  part[t] = sum; __syncthreads();
  for (int off = 1; off < 256; off <<= 1){
    unsigned v = (t >= off) ? part[t-off] : 0u;
    __syncthreads();
    part[t] += v;
    __syncthreads();
  }
  unsigned run = (t == 0) ? 0u : part[t-1];
  for (int k = s0; k < s1; ++k){
    row_off[k] = run; run += counts[k];
  }
  if (t == 255) row_off[n] = part[255];
}

__global__ __launch_bounds__(256) void k_fill(const int* __restrict__ ei,
                                              const unsigned* __restrict__ rank,
                                              const unsigned* __restrict__ roff,
                                              unsigned* __restrict__ si,
                                              unsigned* __restrict__ sj,
                                              unsigned* __restrict__ se, int ne){
  int e = blockIdx.x*256 + threadIdx.x;
  if (e >= ne) return;
  const int i = ei[e];
  const unsigned pos = roff[i] + rank[e];
  si[pos] = (unsigned)i;
  sj[pos] = (unsigned)ei[ne + e];
  se[pos] = (unsigned)e;
}

// ------------------------------ node projections ----------------------------
// Block = 32 nodes, 256 threads.  s tile TRANSPOSED in LDS: stT[k][node].

#define BN 32

__device__ __forceinline__ void pass256(const float* __restrict__ W,
                                        const float stT[64][40], int cg, int sl,
                                        float acc[8][4]){
  #pragma unroll
  for (int i=0;i<8;i++){ acc[i][0]=0.f; acc[i][1]=0.f; acc[i][2]=0.f; acc[i][3]=0.f; }
  #pragma unroll 4
  for (int k = 0; k < 64; ++k){
    const float4 w  = *(const float4*)(W + (size_t)k*256 + cg*4);
    const float4 n0 = *(const float4*)&stT[k][sl*8];
    const float4 n1 = *(const float4*)&stT[k][sl*8+4];
    acc[0][0]+=n0.x*w.x; acc[0][1]+=n0.x*w.y; acc[0][2]+=n0.x*w.z; acc[0][3]+=n0.x*w.w;
    acc[1][0]+=n0.y*w.x; acc[1][1]+=n0.y*w.y; acc[1][2]+=n0.y*w.z; acc[1][3]+=n0.y*w.w;
    acc[2][0]+=n0.z*w.x; acc[2][1]+=n0.z*w.y; acc[2][2]+=n0.z*w.z; acc[2][3]+=n0.z*w.w;
    acc[3][0]+=n0.w*w.x; acc[3][1]+=n0.w*w.y; acc[3][2]+=n0.w*w.z; acc[3][3]+=n0.w*w.w;
    acc[4][0]+=n1.x*w.x; acc[4][1]+=n1.x*w.y; acc[4][2]+=n1.x*w.z; acc[4][3]+=n1.x*w.w;
    acc[5][0]+=n1.y*w.x; acc[5][1]+=n1.y*w.y; acc[5][2]+=n1.y*w.z; acc[5][3]+=n1.y*w.w;
    acc[6][0]+=n1.z*w.x; acc[6][1]+=n1.z*w.y; acc[6][2]+=n1.z*w.z; acc[6][3]+=n1.z*w.w;
    acc[7][0]+=n1.w*w.x; acc[7][1]+=n1.w*w.y; acc[7][2]+=n1.w*w.z; acc[7][3]+=n1.w*w.w;
  }
}

__device__ __forceinline__ void pass96(const float* __restrict__ W,
                                       const float stT[64][40], int cgp, int slp,
                                       float acc[4][4]){
  #pragma unroll
  for (int i=0;i<4;i++){ acc[i][0]=0.f; acc[i][1]=0.f; acc[i][2]=0.f; acc[i][3]=0.f; }
  if (cgp >= 24) return;
  #pragma unroll 4
  for (int k = 0; k < 64; ++k){
    const float4 w = *(const float4*)(W + (size_t)k*96 + cgp*4);
    const float4 nv = *(const float4*)&stT[k][slp*4];
    acc[0][0]+=nv.x*w.x; acc[0][1]+=nv.x*w.y; acc[0][2]+=nv.x*w.z; acc[0][3]+=nv.x*w.w;
    acc[1][0]+=nv.y*w.x; acc[1][1]+=nv.y*w.y; acc[1][2]+=nv.y*w.z; acc[1][3]+=nv.y*w.w;
    acc[2][0]+=nv.z*w.x; acc[2][1]+=nv.z*w.y; acc[2][2]+=nv.z*w.z; acc[2][3]+=nv.z*w.w;
    acc[3][0]+=nv.w*w.x; acc[3][1]+=nv.w*w.y; acc[3][2]+=nv.w*w.z; acc[3][3]+=nv.w*w.w;
  }
}

__global__ __launch_bounds__(256) void k_proj(
    const float* __restrict__ s, const float* __restrict__ quat, const float* __restrict__ trans,
    const float* __restrict__ Wqs, const float* __restrict__ Wks, const float* __restrict__ Wvs,
    const float* __restrict__ Wqv, const float* __restrict__ Wkv, const float* __restrict__ Wvv,
    unsigned* __restrict__ qs, unsigned* __restrict__ ks, float* __restrict__ vs,
    unsigned* __restrict__ qv, unsigned* __restrict__ kv, float* __restrict__ vv, int n)
{
  __shared__ float stT[64][40];    // transposed s tile (k-major), 16B-aligned cols
  __shared__ float pt[BN][97];     // point staging (x:0..31, y:32..63, z:64..95)
  const int tid = threadIdx.x;
  const int node0 = blockIdx.x * BN;

  #pragma unroll
  for (int r = 0; r < 2; ++r){
    const int idx = tid + r*256;          // float4 index
    const int nd = idx >> 4, c4 = idx & 15;
    const int g = node0 + nd;
    float4 v = make_float4(0.f,0.f,0.f,0.f);
    if (g < n) v = *(const float4*)(s + (size_t)g*64 + c4*4);
    stT[c4*4+0][nd]=v.x; stT[c4*4+1][nd]=v.y; stT[c4*4+2][nd]=v.z; stT[c4*4+3][nd]=v.w;
  }
  __syncthreads();

  const int cg = tid & 63, sl = tid >> 6;
  const int cgp = tid & 31, slp = tid >> 5;
  float acc[8][4];

  pass256(Wqs, stT, cg, sl, acc);
  #pragma unroll
  for (int i=0;i<8;i++){
    const int g = node0 + sl*8 + i;
    if (g < n){
      uint2 u; u.x = pack2(acc[i][0],acc[i][1]); u.y = pack2(acc[i][2],acc[i][3]);
      *(uint2*)(qs + (size_t)g*128 + cg*2) = u;
    }
  }
  pass256(Wks, stT, cg, sl, acc);
  #pragma unroll
  for (int i=0;i<8;i++){
    const int g = node0 + sl*8 + i;
    if (g < n){
      uint2 u; u.x = pack2(acc[i][0],acc[i][1]); u.y = pack2(acc[i][2],acc[i][3]);
      *(uint2*)(ks + (size_t)g*128 + cg*2) = u;
    }
  }
  pass256(Wvs, stT, cg, sl, acc);
  #pragma unroll
  for (int i=0;i<8;i++){
    const int g = node0 + sl*8 + i;
    if (g < n){
      float4 f; f.x=acc[i][0]; f.y=acc[i][1]; f.z=acc[i][2]; f.w=acc[i][3];
      *(float4*)(vs + (size_t)g*256 + cg*4) = f;
    }
  }

  float pac[4][4];

  // q_v: rotate + translate -> bf16
  pass96(Wqv, stT, cgp, slp, pac);
  __syncthreads();
  if (cgp < 24){
    #pragma unroll
    for (int i=0;i<4;i++){
      #pragma unroll
      for (int c=0;c<4;c++) pt[slp*4+i][cgp*4+c] = pac[i][c];
    }
  }
  __syncthreads();
  #pragma unroll
  for (int r = 0; r < 2; ++r){
    const int t2 = tid + r*256;
    const int nd = t2 >> 4, pp = t2 & 15;
    const int g = node0 + nd;
    if (g < n){
      const float4 q4 = *(const float4*)(quat + (size_t)g*4);
      const float tx = trans[(size_t)g*3], ty = trans[(size_t)g*3+1], tz = trans[(size_t)g*3+2];
      float x0,y0,z0,x1,y1,z1;
      quat_rot(q4.x,q4.y,q4.z,q4.w, pt[nd][2*pp],   pt[nd][32+2*pp],   pt[nd][64+2*pp],   x0,y0,z0);
      quat_rot(q4.x,q4.y,q4.z,q4.w, pt[nd][2*pp+1], pt[nd][32+2*pp+1], pt[nd][64+2*pp+1], x1,y1,z1);
      x0+=tx; y0+=ty; z0+=tz; x1+=tx; y1+=ty; z1+=tz;
      unsigned* d = qv + (size_t)g*48 + pp*3;
      d[0] = pack2(x0,y0); d[1] = pack2(z0,x1); d[2] = pack2(y1,z1);
    }
  }

  // k_v: rotate + translate -> bf16
  pass96(Wkv, stT, cgp, slp, pac);
  __syncthreads();
  if (cgp < 24){
    #pragma unroll
    for (int i=0;i<4;i++){
      #pragma unroll
      for (int c=0;c<4;c++) pt[slp*4+i][cgp*4+c] = pac[i][c];
    }
  }
  __syncthreads();
  #pragma unroll
  for (int r = 0; r < 2; ++r){
    const int t2 = tid + r*256;
    const int nd = t2 >> 4, pp = t2 & 15;
    const int g = node0 + nd;
    if (g < n){
      const float4 q4 = *(const float4*)(quat + (size_t)g*4);
      const float tx = trans[(size_t)g*3], ty = trans[(size_t)g*3+1], tz = trans[(size_t)g*3+2];
      float x0,y0,z0,x1,y1,z1;
      quat_rot(q4.x,q4.y,q4.z,q4.w, pt[nd][2*pp],   pt[nd][32+2*pp],   pt[nd][64+2*pp],   x0,y0,z0);
      quat_rot(q4.x,q4.y,q4.z,q4.w, pt[nd][2*pp+1], pt[nd][32+2*pp+1], pt[nd][64+2*pp+1], x1,y1,z1);
      x0+=tx; y0+=ty; z0+=tz; x1+=tx; y1+=ty; z1+=tz;
      unsigned* d = kv + (size_t)g*48 + pp*3;
      d[0] = pack2(x0,y0); d[1] = pack2(z0,x1); d[2] = pack2(y1,z1);
    }
  }

  // v_v: raw (pre-rotation) points == out_vec; f32 PLANE layout
  pass96(Wvv, stT, cgp, slp, pac);
  __syncthreads();
  if (cgp < 24){
    #pragma unroll
    for (int i=0;i<4;i++){
      #pragma unroll
      for (int c=0;c<4;c++) pt[slp*4+i][cgp*4+c] = pac[i][c];
    }
  }
  __syncthreads();
  #pragma unroll
  for (int r = 0; r < 12; ++r){
    const int idx = tid + r*256;
    const int nd = idx / 96, col = idx - nd*96;
    const int g = node0 + nd;
    if (g < n) vv[(size_t)g*96 + col] = pt[nd][col];
  }
}

// ------------------------------- edge kernel -------------------------------
// R2-proven structure: 1 thread per CSR edge, everything in registers.

__global__ __launch_bounds__(256) void k_edge(
    const float* __restrict__ z,
    const unsigned* __restrict__ si, const unsigned* __restrict__ sj, const unsigned* __restrict__ se,
    const float* __restrict__ Wb,  const float* __restrict__ bb,
    const float* __restrict__ Wdz, const float* __restrict__ bdz,
    const float* __restrict__ hwts,
    const unsigned* __restrict__ qs, const unsigned* __restrict__ ks,
    const unsigned* __restrict__ qv, const unsigned* __restrict__ kv,
    float* __restrict__ logits, unsigned* __restrict__ pz, int ne)
{
  const int p = blockIdx.x*256 + threadIdx.x;
  if (p >= ne) return;
  const unsigned i = si[p], j = sj[p], e = se[p];

  // ---- bias (z@Wb) and pair (z@Wdz) ----
  float b4[4];  b4[0]=b4[1]=b4[2]=b4[3]=0.f;
  float pacc[16];
  #pragma unroll
  for (int c=0;c<16;c++) pacc[c]=0.f;
  const float* zr = z + (size_t)e*64;
  #pragma unroll
  for (int k4 = 0; k4 < 16; ++k4){
    const float4 zv = *(const float4*)(zr + 4*k4);
    #pragma unroll
    for (int kk = 0; kk < 4; ++kk){
      const int k = 4*k4 + kk;
      const float zk = (kk==0)?zv.x:((kk==1)?zv.y:((kk==2)?zv.z:zv.w));
      const float4 wb = *(const float4*)(Wb + k*4);
      b4[0]+=zk*wb.x; b4[1]+=zk*wb.y; b4[2]+=zk*wb.z; b4[3]+=zk*wb.w;
      const float* wd = Wdz + k*16;
      const float4 w0=*(const float4*)(wd), w1=*(const float4*)(wd+4),
                   w2=*(const float4*)(wd+8), w3=*(const float4*)(wd+12);
      pacc[ 0]+=zk*w0.x; pacc[ 1]+=zk*w0.y; pacc[ 2]+=zk*w0.z; pacc[ 3]+=zk*w0.w;
      pacc[ 4]+=zk*w1.x; pacc[ 5]+=zk*w1.y; pacc[ 6]+=zk*w1.z; pacc[ 7]+=zk*w1.w;
      pacc[ 8]+=zk*w2.x; pacc[ 9]+=zk*w2.y; pacc[10]+=zk*w2.z; pacc[11]+=zk*w2.w;
      pacc[12]+=zk*w3.x; pacc[13]+=zk*w3.y; pacc[14]+=zk*w3.z; pacc[15]+=zk*w3.w;
    }
  }
  #pragma unroll
  for (int c=0;c<16;c++) pacc[c] += bdz[c];
  { uint4 u0, u1;
    u0.x=pack2(pacc[0],pacc[1]);   u0.y=pack2(pacc[2],pacc[3]);
    u0.z=pack2(pacc[4],pacc[5]);   u0.w=pack2(pacc[6],pacc[7]);
    u1.x=pack2(pacc[8],pacc[9]);   u1.y=pack2(pacc[10],pacc[11]);
    u1.z=pack2(pacc[12],pacc[13]); u1.w=pack2(pacc[14],pacc[15]);
    uint4* d = (uint4*)(pz + (size_t)p*8);
    d[0]=u0; d[1]=u1; }

  // ---- scalar attention dot: k_s[i] . q_s[j] per head ----
  const uint4* kr = (const uint4*)(ks + (size_t)i*128);
  const uint4* qr = (const uint4*)(qs + (size_t)j*128);
  float sdot[4];
  #pragma unroll
  for (int h = 0; h < 4; ++h){
    float acc = 0.f;
    #pragma unroll
    for (int c = 0; c < 8; ++c){
      const uint4 a = kr[h*8+c];
      const uint4 b = qr[h*8+c];
      acc += bflo(a.x)*bflo(b.x) + bfhi(a.x)*bfhi(b.x);
      acc += bflo(a.y)*bflo(b.y) + bfhi(a.y)*bfhi(b.y);
      acc += bflo(a.z)*bflo(b.z) + bfhi(a.z)*bfhi(b.z);
      acc += bflo(a.w)*bflo(b.w) + bfhi(a.w)*bfhi(b.w);
    }
    sdot[h] = acc;
  }

  // ---- vector attention: sum_p |q_v[i]-k_v[j]|^2 per head ----
  const uint4* qvr = (const uint4*)(qv + (size_t)i*48);
  const uint4* kvr = (const uint4*)(kv + (size_t)j*48);
  float vsum[4];
  #pragma unroll
  for (int h = 0; h < 4; ++h){
    float acc = 0.f;
    #pragma unroll
    for (int c = 0; c < 3; ++c){
      const uint4 a = qvr[h*3+c];
      const uint4 b = kvr[h*3+c];
      float d;
      d = bflo(a.x)-bflo(b.x); acc += d*d;  d = bfhi(a.x)-bfhi(b.x); acc += d*d;
      d = bflo(a.y)-bflo(b.y); acc += d*d;  d = bfhi(a.y)-bfhi(b.y); acc += d*d;
      d = bflo(a.z)-bflo(b.z); acc += d*d;  d = bfhi(a.z)-bfhi(b.z); acc += d*d;
      d = bflo(a.w)-bflo(b.w); acc += d*d;  d = bfhi(a.w)-bfhi(b.w); acc += d*d;
    }
    vsum[h] = acc;
  }

  float4 lg;
  {
    float l[4];
    #pragma unroll
    for (int h = 0; h < 4; ++h){
      const float hw = log1pf(__expf(hwts[h]));   // softplus
      l[h] = C_SQRT83*sdot[h] + C_SQRT13*(b4[h] + bb[h]) + C_VEC*hw*vsum[h];
    }
    lg.x=l[0]; lg.y=l[1]; lg.z=l[2]; lg.w=l[3];
  }
  *(float4*)(logits + (size_t)p*4) = lg;
}

// ----------------------- wave-per-node softmax + pair -----------------------
// Registers + shuffles only.  Phase 1: lane=edge, per-head max then sum.
// Phase 2: lane=(e4,c) -> 4 edges/iter, acc[h] per lane, butterfly over e4.

__global__ __launch_bounds__(256) void k_soft(
    const float* __restrict__ logits, const unsigned* __restrict__ pz,
    const unsigned* __restrict__ row_off, float* __restrict__ out_pair, int n)
{
  const int node = blockIdx.x*4 + (threadIdx.x >> 6);
  if (node >= n) return;
  const int lane = threadIdx.x & 63;
  const int beg = (int)row_off[node], end = (int)row_off[node+1];

  // ---- phase 1: per-head max and sum (lane-parallel over edges) ----
  float m[4] = {-3.0e38f,-3.0e38f,-3.0e38f,-3.0e38f};
  for (int p = beg + lane; p < end; p += 64){
    const float4 l = *(const float4*)(logits + (size_t)p*4);
    m[0]=fmaxf(m[0],l.x); m[1]=fmaxf(m[1],l.y); m[2]=fmaxf(m[2],l.z); m[3]=fmaxf(m[3],l.w);
  }
  #pragma unroll
  for (int msk = 1; msk < 64; msk <<= 1){
    #pragma unroll
    for (int h=0;h<4;h++) m[h] = fmaxf(m[h], __shfl_xor(m[h], msk));
  }
  float S[4] = {0.f,0.f,0.f,0.f};
  for (int p = beg + lane; p < end; p += 64){
    const float4 l = *(const float4*)(logits + (size_t)p*4);
    S[0]+=__expf(l.x-m[0]); S[1]+=__expf(l.y-m[1]);
    S[2]+=__expf(l.z-m[2]); S[3]+=__expf(l.w-m[3]);
  }
  #pragma unroll
  for (int msk = 1; msk < 64; msk <<= 1){
    #pragma unroll
    for (int h=0;h<4;h++) S[h] += __shfl_xor(S[h], msk);
  }
  float inv[4];
  #pragma unroll
  for (int h=0;h<4;h++) inv[h] = (S[h] > 0.f) ? (1.f/S[h]) : 0.f;

  // ---- phase 2: weighted pair aggregation ----
  const int e4 = lane >> 4, c = lane & 15;
  float acc[4] = {0.f,0.f,0.f,0.f};
  for (int base = beg; base < end; base += 4){
    const int p = base + e4;
    if (p < end){
      const float4 l = *(const float4*)(logits + (size_t)p*4);
      const unsigned u = pz[(size_t)p*8 + (c>>1)];
      const float pzv = (c & 1) ? bfhi(u) : bflo(u);
      acc[0] += __expf(l.x-m[0]) * pzv;
      acc[1] += __expf(l.y-m[1]) * pzv;
      acc[2] += __expf(l.z-m[2]) * pzv;
      acc[3] += __expf(l.w-m[3]) * pzv;
    }
  }
  #pragma unroll
  for (int msk = 16; msk < 64; msk <<= 1){
    #pragma unroll
    for (int h=0;h<4;h++) acc[h] += __shfl_xor(acc[h], msk);
  }
  const int hOut = lane >> 4;          // output layout: [h*16 + c]
  out_pair[(size_t)node*64 + lane] = acc[hOut] * inv[hOut];
}

// --------------------- feats assembly + output GEMM ------------------------

__global__ __launch_bounds__(256) void k_out(
    const float* __restrict__ vs, const float* __restrict__ vv,
    const float* __restrict__ out_pair, const unsigned* __restrict__ row_off,
    const float* __restrict__ quat, const float* __restrict__ trans,
    const float* __restrict__ Wout, const float* __restrict__ bout,
    float* __restrict__ out, int n)
{
  __shared__ float feats[32][448];
  __shared__ int degs[32];
  const int tid = threadIdx.x;
  const int node0 = blockIdx.x*32;

  if (tid < 32){
    const int g = node0 + tid;
    degs[tid] = (g < n) ? (int)(row_off[g+1] - row_off[g]) : 1;
  }
  __syncthreads();

  for (int x = tid; x < 32*256; x += 256){
    const int nd = x >> 8, c = x & 255;
    const int g = node0 + nd;
    feats[nd][c] = (g < n && degs[nd] > 0) ? vs[(size_t)g*256 + c] : 0.f;
  }
  for (int x = tid; x < 32*64; x += 256){
    const int nd = x >> 6, c = x & 63;
    const int g = node0 + nd;
    feats[nd][384 + c] = (g < n) ? out_pair[(size_t)g*64 + c] : 0.f;
  }
  for (int x = tid; x < 32*32; x += 256){
    const int nd = x >> 5, pt = x & 31;
    const int g = node0 + nd;
    float X=0.f, Y=0.f, Z=0.f;
    if (g < n){
      if (degs[nd] > 0){
        X = vv[(size_t)g*96 + pt];
        Y = vv[(size_t)g*96 + 32 + pt];
        Z = vv[(size_t)g*96 + 64 + pt];
      } else {
        const float4 q4 = *(const float4*)(quat + (size_t)g*4);
        const float tx = trans[(size_t)g*3], ty = trans[(size_t)g*3+1], tz = trans[(size_t)g*3+2];
        quat_rot(q4.x, -q4.y, -q4.z, -q4.w, -tx, -ty, -tz, X, Y, Z);
      }
    }
    feats[nd][256 + pt] = X;
    feats[nd][288 + pt] = Y;
    feats[nd][320 + pt] = Z;
    feats[nd][352 + pt] = sqrtf(X*X + Y*Y + Z*Z + 1e-8f);
  }
  __syncthreads();

  const int lane = tid & 63;
  const int wave = tid >> 6;
  float acc[8];
  #pragma unroll
  for (int q8=0;q8<8;q8++) acc[q8]=0.f;

  for (int k0 = 0; k0 < 448; k0 += 4){
    const float w0 = Wout[(size_t)(k0+0)*64 + lane];
    const float w1 = Wout[(size_t)(k0+1)*64 + lane];
    const float w2 = Wout[(size_t)(k0+2)*64 + lane];
    const float w3 = Wout[(size_t)(k0+3)*64 + lane];
    #pragma unroll
    for (int q8 = 0; q8 < 8; ++q8){
      const float4 f = *(const float4*)&feats[wave*8 + q8][k0];
      acc[q8] += f.x*w0 + f.y*w1 + f.z*w2 + f.w*w3;
    }
  }
  const float bo = bout[lane];
  #pragma unroll
  for (int q8 = 0; q8 < 8; ++q8){
    const int g = node0 + wave*8 + q8;
    if (g < n) out[(size_t)g*64 + lane] = acc[q8] + bo;
  }
}

// --------------------------------- launch ----------------------------------

extern "C" void kernel_launch(void* const* d_in, const int* in_sizes, int n_in,
                              void* d_out, int out_size, void* d_ws, size_t ws_size,
                              hipStream_t stream) {
  const float* s     = (const float*)d_in[0];
  const float* z     = (const float*)d_in[1];
  const int*   ei    = (const int*)  d_in[2];
  const float* quat  = (const float*)d_in[3];
  const float* trans = (const float*)d_in[4];
  const float* Wqs   = (const float*)d_in[5];
  const float* Wks   = (const float*)d_in[6];
  const float* Wvs   = (const float*)d_in[7];
  const float* Wqv   = (const float*)d_in[8];
  const float* Wkv   = (const float*)d_in[9];
  const float* Wvv   = (const float*)d_in[10];
  const float* Wb    = (const float*)d_in[11];
  const float* bb    = (const float*)d_in[12];
  const float* Wdz   = (const float*)d_in[13];
  const float* bdz   = (const float*)d_in[14];
  const float* hwts  = (const float*)d_in[15];
  const float* Wout  = (const float*)d_in[16];
  const float* bout  = (const float*)d_in[17];
  float* out = (float*)d_out;

  const int n  = in_sizes[0] / 64;   // 20000
  const int ne = in_sizes[1] / 64;   // 640000

  size_t off = 0;
  char* base = (char*)d_ws;
  auto take = [&](size_t bytes)->char* {
    char* p = base + off;
    off += (bytes + 255) & ~(size_t)255;
    return p;
  };
  unsigned* qs     = (unsigned*)take((size_t)n*512);    // bf16 N x 256
  unsigned* ks     = (unsigned*)take((size_t)n*512);    // bf16 N x 256
  unsigned* qvt    = (unsigned*)take((size_t)n*192);    // bf16 N x 96 (rot + t)
  unsigned* kvt    = (unsigned*)take((size_t)n*192);    // bf16 N x 96 (rot + t)
  float*    vs     = (float*)   take((size_t)n*1024);   // f32  N x 256
  float*    vv     = (float*)   take((size_t)n*384);    // f32  N x 96 (raw, planes)
  float*    logits = (float*)   take((size_t)ne*16);    // f32  E x 4 (CSR order)
  unsigned* pz     = (unsigned*)take((size_t)ne*32);    // bf16 E x 16 (CSR order)
  unsigned* counts = (unsigned*)take((size_t)n*4);
  unsigned* roff   = (unsigned*)take((size_t)(n+1)*4);
  unsigned* rank   = (unsigned*)take((size_t)ne*4);
  unsigned* si     = (unsigned*)take((size_t)ne*4);
  unsigned* sj     = (unsigned*)take((size_t)ne*4);
  unsigned* se     = (unsigned*)take((size_t)ne*4);
  float*    opair  = (float*)   take((size_t)n*256);    // f32  N x 64
  (void)ws_size; (void)n_in; (void)out_size;

  const int gbE = (ne + 255) / 256;

  hipMemsetAsync(counts, 0, (size_t)n*4, stream);
  k_count<<<gbE, 256, 0, stream>>>(ei, counts, rank, ne);
  k_scan <<<1,   256, 0, stream>>>(counts, roff, n);
  k_fill <<<gbE, 256, 0, stream>>>(ei, rank, roff, si, sj, se, ne);
  k_proj <<<(n + BN - 1)/BN, 256, 0, stream>>>(s, quat, trans, Wqs, Wks, Wvs, Wqv, Wkv, Wvv,
                                               qs, ks, vs, qvt, kvt, vv, n);
  k_edge <<<gbE, 256, 0, stream>>>(z, si, sj, se, Wb, bb, Wdz, bdz, hwts,
                                   qs, ks, qvt, kvt, logits, pz, ne);
  k_soft <<<(n + 3)/4, 256, 0, stream>>>(logits, pz, roff, opair, n);
  k_out  <<<(n + 31)/32, 256, 0, stream>>>(vs, vv, opair, roff, quat, trans,
                                           Wout, bout, out, n);
}